// Round 1
// baseline (334.030 us; speedup 1.0000x reference)
//
#include <hip/hip_runtime.h>
#include <hip/hip_bf16.h>

// Problem constants (shapes are fixed by the reference)
#define XS   2
#define NP   96
#define NREP 4
#define MAXD 7
#define NCG  4
#define NCH  16
#define NLAY 3
// L_INPUT = 3, DIMS[3] = 7 (hardcoded; the 'l' input is always 3)

// packed (rep,dim) index tables: 16 = 1+3+5+7 entries
__constant__ int P2R_c[16] = {0, 1,1,1, 2,2,2,2,2, 3,3,3,3,3,3,3};
__constant__ int P2D_c[16] = {0, 0,1,2, 0,1,2,3,4, 0,1,2,3,4,5,6};
__constant__ int DIMS_c[4] = {1,3,5,7};
__constant__ int OFF_c[4]  = {0,1,4,9};

__device__ inline float2 cmul(float2 a, float2 b){
    return make_float2(a.x*b.x - a.y*b.y, a.x*b.y + a.y*b.x);
}
__device__ inline float2 cmadd(float2 acc, float2 a, float2 b){
    acc.x += a.x*b.x - a.y*b.y;
    acc.y += a.x*b.y + a.y*b.x;
    return acc;
}

// cgf[k][qr16][s7][t7] = sum_g cg[g,3,s,3,t,q,r] * f[k,q,g]   (complex)
__global__ void prep_cgf_kernel(const float* __restrict__ cg,
                                const float* __restrict__ f,
                                float* __restrict__ cgf){
    int idx = blockIdx.x*blockDim.x + threadIdx.x;
    if (idx >= NLAY*16*49) return;
    int k  = idx / (16*49);
    int rem = idx % (16*49);
    int qr = rem / 49;
    int st = rem % 49;
    int s = st / 7, t = st % 7;
    int q = P2R_c[qr], r = P2D_c[qr];
    float2 acc = make_float2(0.f, 0.f);
    for (int g = 0; g < NCG; ++g){
        // cg shape (4,4,7,4,7,4,7,2): [g][l][s][m][t][q][r][z], l=m=3
        const float* cgp = cg + ((((((size_t)g*4+3)*7 + s)*4 + 3)*7 + t)*4 + q)*7*2 + r*2;
        float2 cgv = make_float2(cgp[0], cgp[1]);
        const float* fp = f + ((k*4 + q)*4 + g)*2;
        float2 fv = make_float2(fp[0], fp[1]);
        acc = cmadd(acc, cgv, fv);
    }
    cgf[idx*2]   = acc.x;
    cgf[idx*2+1] = acc.y;
}

// pack V: (x,j,m,c,t,z) dense MAXD=7 -> Vp[x][j][mt16][c16] complex
__global__ void pack_V_kernel(const float* __restrict__ Vin,
                              float* __restrict__ Vp){
    int idx = blockIdx.x*blockDim.x + threadIdx.x;
    if (idx >= XS*NP*16*16) return;
    int c  = idx & 15;
    int mt = (idx >> 4) & 15;
    int xj = idx >> 8;
    int m = P2R_c[mt], t = P2D_c[mt];
    const float* p = Vin + ((((size_t)xj*4 + m)*16 + c)*7 + t)*2;
    Vp[idx*2]   = p[0];
    Vp[idx*2+1] = p[1];
}

// One layer: Vout[x][i][qr][d] = sum_{j,g,ls,mt,c} cg * filt * Vin * W
__global__ __launch_bounds__(256)
void layer_kernel(const float* __restrict__ X,
                  const float* __restrict__ cg,
                  const float* __restrict__ cgf_k,  // [16][49] complex
                  const float* __restrict__ W_k,    // [q][c][g][d] complex
                  const float* __restrict__ Vin,    // packed [x][j][mt][c]
                  float* __restrict__ Vout)         // packed [x][i][qr][d]
{
    __shared__ float2 dX_s[NP][7];
    __shared__ float2 filt_s[NP][16];
    __shared__ float2 T_s[16][256];    // [ls][mt*16+c]
    __shared__ float2 S_s[4][16][16];  // [g][qr][c]

    const int tid = threadIdx.x;
    const int bx  = blockIdx.x;        // x*NP + i
    const int x = bx / NP, i = bx % NP;

    // phase 0a: dX[j][s] = X[x,j,s] - X[x,i,s]
    for (int e = tid; e < NP*7; e += 256){
        int j = e / 7, s = e % 7;
        const float* Xj = X + (((size_t)x*NP + j)*7 + s)*2;
        const float* Xi = X + (((size_t)x*NP + i)*7 + s)*2;
        dX_s[j][s] = make_float2(Xj[0]-Xi[0], Xj[1]-Xi[1]);
    }
    __syncthreads();

    // phase 0b: filt[j][qr] = [q==3]*dX[r] + sum_{s,t} cgf[qr][s][t]*dX[s]*dX[t]
    const float2* cgf2 = (const float2*)cgf_k;
    for (int e = tid; e < NP*16; e += 256){
        int j = e >> 4, qr = e & 15;
        float2 acc = make_float2(0.f, 0.f);
        for (int s = 0; s < 7; ++s){
            float2 ds = dX_s[j][s];
            #pragma unroll
            for (int t = 0; t < 7; ++t){
                float2 cf = cgf2[(qr*7 + s)*7 + t];
                float2 dd = cmul(ds, dX_s[j][t]);
                acc = cmadd(acc, cf, dd);
            }
        }
        if (qr >= 9){ // q==3, r=qr-9: base term
            float2 dv = dX_s[j][qr-9];
            acc.x += dv.x; acc.y += dv.y;
        }
        filt_s[j][qr] = acc;
    }
    __syncthreads();

    // phase 1: T[ls][mtc] = sum_j filt[j][ls] * Vin[x][j][mtc]
    {
        const int mtc = tid;
        float2 acc[16];
        #pragma unroll
        for (int ls = 0; ls < 16; ++ls) acc[ls] = make_float2(0.f, 0.f);
        const float2* Vb = (const float2*)Vin + (size_t)x*NP*256 + mtc;
        for (int j = 0; j < NP; ++j){
            float2 v = Vb[(size_t)j*256];
            #pragma unroll
            for (int ls = 0; ls < 16; ++ls){
                acc[ls] = cmadd(acc[ls], filt_s[j][ls], v);
            }
        }
        #pragma unroll
        for (int ls = 0; ls < 16; ++ls) T_s[ls][mtc] = acc[ls];
    }
    __syncthreads();

    // phase 2: S[g][qr][c] = sum_{ls,mt} cg[g,l,s,m,t,q,r] * T[ls][mt][c]
    {
        const int c = tid & 15, qr = tid >> 4;
        const int q = P2R_c[qr], r = P2D_c[qr];
        float2 accg[4];
        #pragma unroll
        for (int g = 0; g < 4; ++g) accg[g] = make_float2(0.f, 0.f);
        for (int ls = 0; ls < 16; ++ls){
            int l = P2R_c[ls], s = P2D_c[ls];
            for (int mt = 0; mt < 16; ++mt){
                int m = P2R_c[mt], t = P2D_c[mt];
                int lo = (l > m) ? (l - m) : (m - l);
                if (q < lo || q > l + m) continue;  // cg is zero there anyway
                float2 tv = T_s[ls][mt*16 + c];
                const float2* cgp = (const float2*)cg +
                    (((((size_t)l*7 + s)*4 + m)*7 + t)*4 + q)*7 + r;
                #pragma unroll
                for (int g = 0; g < 4; ++g){
                    float2 cgv = cgp[(size_t)g*21952]; // g-stride in float2
                    accg[g] = cmadd(accg[g], cgv, tv);
                }
            }
        }
        #pragma unroll
        for (int g = 0; g < 4; ++g) S_s[g][qr][c] = accg[g];
    }
    __syncthreads();

    // phase 3: Vout[qr][d] = sum_{g,c} S[g][qr][c] * W[q][c][g][d]
    {
        const int d = tid & 15, qr = tid >> 4;
        const int q = P2R_c[qr];
        float2 acc = make_float2(0.f, 0.f);
        for (int g = 0; g < 4; ++g){
            #pragma unroll
            for (int c = 0; c < 16; ++c){
                float2 sv = S_s[g][qr][c];
                const float2* wp = (const float2*)W_k + ((((size_t)q*16 + c)*4 + g)*16 + d);
                acc = cmadd(acc, sv, *wp);
            }
        }
        ((float2*)Vout)[((size_t)x*NP + i)*256 + qr*16 + d] = acc;
    }
}

// unpack final packed V -> d_out (x,i,q,d,r,z), zeros at r >= DIMS[q]
__global__ void unpack_V_kernel(const float* __restrict__ Vp,
                                float* __restrict__ out){
    int idx = blockIdx.x*blockDim.x + threadIdx.x;
    if (idx >= XS*NP*4*16*7) return;
    int r  = idx % 7;
    int d  = (idx / 7) % 16;
    int q  = (idx / (7*16)) % 4;
    int xi = idx / (7*16*4);
    float2 v = make_float2(0.f, 0.f);
    if (r < DIMS_c[q]){
        v = ((const float2*)Vp)[(size_t)xi*256 + (OFF_c[q] + r)*16 + d];
    }
    ((float2*)out)[idx] = v;
}

extern "C" void kernel_launch(void* const* d_in, const int* in_sizes, int n_in,
                              void* d_out, int out_size, void* d_ws, size_t ws_size,
                              hipStream_t stream) {
    const float* X  = (const float*)d_in[0];
    // d_in[1] is 'l' (always 3, hardcoded)
    const float* V  = (const float*)d_in[2];
    const float* cg = (const float*)d_in[3];
    const float* f  = (const float*)d_in[4];
    const float* W  = (const float*)d_in[5];
    // d_in[6] is C4 (plain complex product, hardcoded)

    float* ws = (float*)d_ws;
    float* cgf   = ws;                       // 3*16*49*2 = 4704 floats
    float* VbufA = ws + 4704;                // 2*96*256*2 = 98304 floats
    float* VbufB = VbufA + XS*NP*256*2;      // 98304 floats

    // precompute per-layer quadratic-filter coefficients
    prep_cgf_kernel<<<(NLAY*16*49 + 255)/256, 256, 0, stream>>>(cg, f, cgf);
    // pack initial V
    pack_V_kernel<<<(XS*NP*256 + 255)/256, 256, 0, stream>>>(V, VbufA);

    float* bufs[2] = {VbufA, VbufB};
    int cur = 0;
    for (int k = 0; k < NLAY; ++k){
        const float* cgf_k = cgf + (size_t)k*16*49*2;
        const float* W_k   = W   + (size_t)k*4*16*4*16*2;
        layer_kernel<<<XS*NP, 256, 0, stream>>>(X, cg, cgf_k, W_k,
                                                bufs[cur], bufs[cur^1]);
        cur ^= 1;
    }
    unpack_V_kernel<<<(XS*NP*4*16*7 + 255)/256, 256, 0, stream>>>(bufs[cur], (float*)d_out);
}

// Round 2
// 281.885 us; speedup vs baseline: 1.1850x; 1.1850x over previous
//
#include <hip/hip_runtime.h>
#include <hip/hip_bf16.h>

// Problem constants (shapes fixed by the reference)
#define XS   2
#define NP   96
#define NLAY 3
// L_INPUT = 3, DIMS = (1,3,5,7), MAX_DIM = 7, NUM_CG = 4, NUM_CH = 16

// packed (rep,dim) index tables: 16 = 1+3+5+7 entries
__constant__ int P2R_c[16] = {0, 1,1,1, 2,2,2,2,2, 3,3,3,3,3,3,3};
__constant__ int P2D_c[16] = {0, 0,1,2, 0,1,2,3,4, 0,1,2,3,4,5,6};
__constant__ int DIMS_c[4] = {1,3,5,7};
__constant__ int OFF_c[4]  = {0,1,4,9};

__device__ inline float2 cmul(float2 a, float2 b){
    return make_float2(a.x*b.x - a.y*b.y, a.x*b.y + a.y*b.x);
}
__device__ inline float2 cmadd(float2 acc, float2 a, float2 b){
    acc.x += a.x*b.x - a.y*b.y;
    acc.y += a.x*b.y + a.y*b.x;
    return acc;
}

// One prep kernel, three flat ranges:
//  [0, 2352)            cgf[k][qr][s][t] = sum_g cg[g,3,s,3,t,q,r]*f[k,q,g]
//  [2352, 2352+16384)   PK[qr][ls][mt][g] = cg[g,l,s,m,t,q,r]  (dense repack)
//  [18736, 18736+49152) pack V -> Vp[x][j][mt16][c16]
#define PREP_TOTAL (2352 + 16384 + 49152)
__global__ void prep_kernel(const float* __restrict__ cg,
                            const float* __restrict__ f,
                            const float* __restrict__ Vin,
                            float* __restrict__ cgf,
                            float* __restrict__ PK,
                            float* __restrict__ Vp){
    int idx = blockIdx.x*256 + threadIdx.x;
    if (idx < 2352){
        int k  = idx / (16*49);
        int rem = idx % (16*49);
        int qr = rem / 49;
        int st = rem % 49;
        int s = st / 7, t = st % 7;
        int q = P2R_c[qr], r = P2D_c[qr];
        float2 acc = make_float2(0.f, 0.f);
        for (int g = 0; g < 4; ++g){
            const float* cgp = cg + (((((((size_t)g*4+3)*7 + s)*4 + 3)*7 + t)*4 + q)*7 + r)*2;
            const float* fp  = f + ((k*4 + q)*4 + g)*2;
            acc = cmadd(acc, make_float2(cgp[0], cgp[1]), make_float2(fp[0], fp[1]));
        }
        cgf[idx*2]   = acc.x;
        cgf[idx*2+1] = acc.y;
    } else if (idx < 2352 + 16384){
        int id = idx - 2352;           // = ((qr*16+ls)*16+mt)*4+g
        int g  = id & 3;
        int mt = (id >> 2) & 15;
        int ls = (id >> 6) & 15;
        int qr = (id >> 10) & 15;
        int l = P2R_c[ls], s = P2D_c[ls];
        int m = P2R_c[mt], t = P2D_c[mt];
        int q = P2R_c[qr], r = P2D_c[qr];
        size_t co = (((((((size_t)g*4 + l)*7 + s)*4 + m)*7 + t)*4 + q)*7 + r);
        PK[id*2]   = cg[co*2];
        PK[id*2+1] = cg[co*2+1];
    } else if (idx < PREP_TOTAL){
        int id = idx - 18736;          // = (xj*16+mt)*16+c
        int c  = id & 15;
        int mt = (id >> 4) & 15;
        int xj = id >> 8;
        int m = P2R_c[mt], t = P2D_c[mt];
        const float* p = Vin + ((((size_t)xj*4 + m)*16 + c)*7 + t)*2;
        Vp[id*2]   = p[0];
        Vp[id*2+1] = p[1];
    }
}

// One layer, one block per (x,i), 1024 threads (16 waves/CU).
__global__ __launch_bounds__(1024)
void layer_kernel(const float* __restrict__ X,
                  const float* __restrict__ cgf_k,  // [16][49] complex
                  const float* __restrict__ PK,     // [qr][ls][mt][g] complex
                  const float* __restrict__ W_k,    // [q][c][g][d] complex
                  const float* __restrict__ Vin,    // packed [x][j][mt][c]
                  float* __restrict__ Vout)         // packed [x][i][qr][d]
{
    __shared__ float2 filt_s[NP][16];     // 12288 B
    __shared__ float2 T_s[16][256];       // 32768 B  [ls][mt*16+c]
    __shared__ char   scratch_raw[11648]; // union region
    float2 (*dX_s)[7] = (float2(*)[7])scratch_raw;       // 96*7*8  = 5376 B
    float2 *cgf_s     = (float2*)(scratch_raw + 5376);   // 784*8   = 6272 B
    float2 *S_s       = (float2*)scratch_raw;            // [g][qr][c] 1024*8 = 8192 B (after phase 0)

    const int tid = threadIdx.x;
    const int x = blockIdx.x / NP, i = blockIdx.x % NP;

    // phase -1/0a: stage cgf + dX in LDS
    if (tid < 784) cgf_s[tid] = ((const float2*)cgf_k)[tid];
    if (tid < NP*7){
        int j = tid / 7, s = tid % 7;
        const float* Xj = X + (((size_t)x*NP + j)*7 + s)*2;
        const float* Xi = X + (((size_t)x*NP + i)*7 + s)*2;
        dX_s[j][s] = make_float2(Xj[0]-Xi[0], Xj[1]-Xi[1]);
    }
    __syncthreads();

    // phase 0b: filt[j][qr] = [q==3]*dX[r] + sum_s dX[s]*(sum_t cgf[qr][s][t]*dX[t])
    for (int e = tid; e < NP*16; e += 1024){
        int j = e >> 4, qr = e & 15;
        const float2* cb = cgf_s + qr*49;
        float2 acc = make_float2(0.f, 0.f);
        #pragma unroll
        for (int s = 0; s < 7; ++s){
            float2 inner = make_float2(0.f, 0.f);
            #pragma unroll
            for (int t = 0; t < 7; ++t)
                inner = cmadd(inner, cb[s*7 + t], dX_s[j][t]);
            acc = cmadd(acc, dX_s[j][s], inner);
        }
        if (qr >= 9){ float2 dv = dX_s[j][qr-9]; acc.x += dv.x; acc.y += dv.y; }
        filt_s[j][qr] = acc;
    }
    __syncthreads();

    // phase 1: T[ls][mtc] = sum_j filt[j][ls]*Vin[x][j][mtc], 4-way j-split
    {
        const int jg  = tid >> 8;      // 0..3
        const int mtc = tid & 255;
        const float2* Vb = (const float2*)Vin + (size_t)x*NP*256 + mtc;
        float2 acc[16];
        #pragma unroll
        for (int ls = 0; ls < 16; ++ls) acc[ls] = make_float2(0.f, 0.f);
        const int j0 = jg*24;
        #pragma unroll 8
        for (int jj = 0; jj < 24; ++jj){
            const int j = j0 + jj;
            float2 v = Vb[(size_t)j*256];
            const float2* fr = filt_s[j];
            #pragma unroll
            for (int ls = 0; ls < 16; ++ls)
                acc[ls] = cmadd(acc[ls], fr[ls], v);
        }
        // staged reduction into T_s
        for (int g = 0; g < 4; ++g){
            if (jg == g){
                if (g == 0){
                    #pragma unroll
                    for (int ls = 0; ls < 16; ++ls) T_s[ls][mtc] = acc[ls];
                } else {
                    #pragma unroll
                    for (int ls = 0; ls < 16; ++ls){
                        float2 tp = T_s[ls][mtc];
                        tp.x += acc[ls].x; tp.y += acc[ls].y;
                        T_s[ls][mtc] = tp;
                    }
                }
            }
            __syncthreads();
        }
    }

    // phase 2: S[g][qr][c] = sum_{ls,mt} PK[qr][ls][mt][g]*T[ls][mt][c], 4-way ls-split
    {
        const int lsq = tid >> 8;      // 0..3
        const int qr  = (tid >> 4) & 15;
        const int c   = tid & 15;
        float2 accg[4];
        #pragma unroll
        for (int g = 0; g < 4; ++g) accg[g] = make_float2(0.f, 0.f);
        #pragma unroll
        for (int lo = 0; lo < 4; ++lo){
            const int ls = lsq*4 + lo;
            #pragma unroll 4
            for (int mt = 0; mt < 16; ++mt){
                float2 tv = T_s[ls][mt*16 + c];
                const float2* pk = (const float2*)PK + (((size_t)(qr*16 + ls)*16 + mt) << 2);
                accg[0] = cmadd(accg[0], pk[0], tv);
                accg[1] = cmadd(accg[1], pk[1], tv);
                accg[2] = cmadd(accg[2], pk[2], tv);
                accg[3] = cmadd(accg[3], pk[3], tv);
            }
        }
        // staged reduction into S_s (aliases dX/cgf scratch - both dead now)
        for (int g4 = 0; g4 < 4; ++g4){
            if (lsq == g4){
                if (g4 == 0){
                    #pragma unroll
                    for (int g = 0; g < 4; ++g) S_s[(g*16 + qr)*16 + c] = accg[g];
                } else {
                    #pragma unroll
                    for (int g = 0; g < 4; ++g){
                        float2 sp = S_s[(g*16 + qr)*16 + c];
                        sp.x += accg[g].x; sp.y += accg[g].y;
                        S_s[(g*16 + qr)*16 + c] = sp;
                    }
                }
            }
            __syncthreads();
        }
    }

    // phase 3: Vout[qr][d] = sum_{g,c} S[g][qr][c]*W[q][c][g][d]
    if (tid < 256){
        const int qr = tid >> 4, d = tid & 15;
        const int q = P2R_c[qr];
        float2 acc = make_float2(0.f, 0.f);
        const float2* Wb = (const float2*)W_k + (size_t)q*16*4*16 + d;
        #pragma unroll 4
        for (int c = 0; c < 16; ++c){
            #pragma unroll
            for (int g = 0; g < 4; ++g){
                float2 sv = S_s[(g*16 + qr)*16 + c];
                float2 wv = Wb[(c*4 + g)*16];
                acc = cmadd(acc, sv, wv);
            }
        }
        ((float2*)Vout)[(size_t)blockIdx.x*256 + tid] = acc;
    }
}

// unpack final packed V -> d_out (x,i,q,d,r,z), zeros at r >= DIMS[q]
__global__ void unpack_V_kernel(const float* __restrict__ Vp,
                                float* __restrict__ out){
    int idx = blockIdx.x*blockDim.x + threadIdx.x;
    if (idx >= XS*NP*4*16*7) return;
    int r  = idx % 7;
    int d  = (idx / 7) % 16;
    int q  = (idx / (7*16)) % 4;
    int xi = idx / (7*16*4);
    float2 v = make_float2(0.f, 0.f);
    if (r < DIMS_c[q]){
        v = ((const float2*)Vp)[(size_t)xi*256 + (OFF_c[q] + r)*16 + d];
    }
    ((float2*)out)[idx] = v;
}

extern "C" void kernel_launch(void* const* d_in, const int* in_sizes, int n_in,
                              void* d_out, int out_size, void* d_ws, size_t ws_size,
                              hipStream_t stream) {
    const float* X  = (const float*)d_in[0];
    // d_in[1] is 'l' (always 3, hardcoded)
    const float* V  = (const float*)d_in[2];
    const float* cg = (const float*)d_in[3];
    const float* f  = (const float*)d_in[4];
    const float* W  = (const float*)d_in[5];
    // d_in[6] is C4 (plain complex product, hardcoded)

    float* ws    = (float*)d_ws;
    float* cgf   = ws;                        // 2352 cplx = 4704 floats
    float* PK    = ws + 4704;                 // 16384 cplx = 32768 floats
    float* VbufA = ws + 4704 + 32768;         // 49152 cplx = 98304 floats
    float* VbufB = VbufA + XS*NP*256*2;       // 98304 floats

    prep_kernel<<<(PREP_TOTAL + 255)/256, 256, 0, stream>>>(cg, f, V, cgf, PK, VbufA);

    float* bufs[2] = {VbufA, VbufB};
    int cur = 0;
    for (int k = 0; k < NLAY; ++k){
        const float* cgf_k = cgf + (size_t)k*16*49*2;
        const float* W_k   = W   + (size_t)k*4*16*4*16*2;
        layer_kernel<<<XS*NP, 1024, 0, stream>>>(X, cgf_k, PK, W_k,
                                                 bufs[cur], bufs[cur^1]);
        cur ^= 1;
    }
    unpack_V_kernel<<<(XS*NP*4*16*7 + 255)/256, 256, 0, stream>>>(bufs[cur], (float*)d_out);
}